// Round 10
// baseline (326.705 us; speedup 1.0000x reference)
//
#include <hip/hip_runtime.h>

#define REP10(X) X(0) X(1) X(2) X(3) X(4) X(5) X(6) X(7) X(8) X(9)

// ---------------------------------------------------------------------------
// prep_kernel: fold BN+conv-bias into scale/shift2; pre-scale attn dw/db by
// log2(e) so softmax uses native v_exp_f32. consts stride 80 per stage:
// [0..10) scale | [10..20) shift2 | [20..70) adw2 | [70..80) adb2
// ---------------------------------------------------------------------------
__device__ __forceinline__ void fold_stage(
    float* dst, const float* g, const float* be, const float* mn,
    const float* vr, const float* cb, const float* adw, const float* adb)
{
  const int tid = threadIdx.x;
  if (tid < 10) {
    const float sc = g[tid] * rsqrtf(vr[tid] + 1e-3f);
    dst[tid]      = sc;
    dst[10 + tid] = (cb[tid] - mn[tid]) * sc + be[tid];
    dst[70 + tid] = adb[tid] * 1.44269504088896340736f;
  }
  if (tid >= 10 && tid < 60)
    dst[10 + tid] = adw[tid - 10] * 1.44269504088896340736f;
}

__global__ void prep_kernel(
    const float* g1, const float* be1, const float* m1, const float* v1,
    const float* cb1, const float* a1dw, const float* a1db,
    const float* g2, const float* be2, const float* m2, const float* v2,
    const float* cb2, const float* a2dw, const float* a2db,
    const float* g3, const float* be3, const float* m3, const float* v3,
    const float* cb3, const float* a3dw, const float* a3db,
    float* consts)
{
  fold_stage(consts,       g1, be1, m1, v1, cb1, a1dw, a1db);
  fold_stage(consts + 80,  g2, be2, m2, v2, cb2, a2dw, a2db);
  fold_stage(consts + 160, g3, be3, m3, v3, cb3, a3dw, a3db);
}

// dnswT[cc][t] = dnsw[t*20+cc]
__global__ void transpose_dnsw(const float* __restrict__ dnsw,
                               float* __restrict__ dnswT)
{
  const int cc = blockIdx.x;
  for (int t = threadIdx.x; t < 988; t += 256)
    dnswT[cc * 988 + t] = dnsw[t * 20 + cc];
}

// ---------------------------------------------------------------------------
// stage_kernel: one fused VIGNet stage, 2 outputs/thread (float2 loads/
// stores). Live set ~55 floats -- under the ~60-float spill threshold this
// problem has shown 6 times (R1-R5, R9: bigger per-thread state => compiler
// parks it in scratch => GBs of phantom HBM traffic).
// block=128 threads, tile=256 outputs, grid=(4, 2, batch-chunk).
// in : [bc][CIN][2][1000] ; out : [bc][10][2][1000]
// ---------------------------------------------------------------------------
template <int CIN>
__global__ __launch_bounds__(128) void stage_kernel(
    const float* __restrict__ in, float* __restrict__ outp, int Tout,
    const float* __restrict__ ck, const float* __restrict__ aK,
    const float* __restrict__ ab, const float* __restrict__ cst)
{
  __shared__ float smm[10][264];
  const int tid = threadIdx.x;      // 0..127
  const int o   = blockIdx.y;
  const int t0  = blockIdx.x * 256;
  const int Tin = Tout + 4;
  const float* __restrict__ inb = in + (size_t)blockIdx.z * (CIN * 2000);

  // ---- Phase A: einsum m_i for pairs of positions -> smm (b64 writes)
  for (int lt = 2 * tid; lt < 260; lt += 256) {
    const int t = t0 + lt;
    if (t < Tin) {                  // t,Tin even -> pair fully valid
#define DECLM(i) float ma##i = ab[i * 2 + o], mb##i = ma##i;
      REP10(DECLM)
#undef DECLM
#pragma unroll
      for (int h = 0; h < 2; ++h)
#pragma unroll
        for (int ci = 0; ci < CIN; ++ci) {
          const float2 xv =
              *reinterpret_cast<const float2*>(inb + (ci * 2 + h) * 1000 + t);
#define FMAM(i) { const float w_ = aK[((i * 2 + h) * CIN + ci) * 2 + o];       \
          ma##i += xv.x * w_; mb##i += xv.y * w_; }
          REP10(FMAM)
#undef FMAM
        }
#define STM(i) *reinterpret_cast<float2*>(&smm[i][lt]) =                       \
          make_float2(ma##i, mb##i);
      REP10(STM)
#undef STM
    }
  }
  __syncthreads();

  // ---- Phase B: 2 outputs per thread (no barriers below -> early-out safe)
  const int lt = 2 * tid;
  const int t  = t0 + lt;
  if (t >= Tout) return;            // t,Tout even -> pair fully valid

  const float* __restrict__ scale  = cst;
  const float* __restrict__ shift2 = cst + 10;
  const float* __restrict__ adw2   = cst + 20;
  const float* __restrict__ adb2   = cst + 70;

  // attention: depthwise from smm (3x ds_read_b64 per head) + native exp2.
  // No max-subtraction: logits are O(0.1); softmax shift-invariant (validated
  // bit-clean in R9).
  float sum0 = 0.f, sum1 = 0.f;
#define ATTN(i) float e##i##0, e##i##1; {                                      \
    const float2 s0 = *reinterpret_cast<const float2*>(&smm[i][lt]);           \
    const float2 s1 = *reinterpret_cast<const float2*>(&smm[i][lt + 2]);       \
    const float2 s2 = *reinterpret_cast<const float2*>(&smm[i][lt + 4]);       \
    const float w0 = adw2[i], w1 = adw2[10 + i], w2 = adw2[20 + i],            \
                w3 = adw2[30 + i], w4 = adw2[40 + i];                          \
    const float bi = adb2[i];                                                  \
    const float ya = bi + s0.x*w0 + s0.y*w1 + s1.x*w2 + s1.y*w3 + s2.x*w4;     \
    const float yb = bi + s0.y*w0 + s1.x*w1 + s1.y*w2 + s2.x*w3 + s2.y*w4;     \
    e##i##0 = exp2f(ya); e##i##1 = exp2f(yb);                                  \
    sum0 += e##i##0; sum1 += e##i##1; }
  REP10(ATTN)
#undef ATTN

  // conv (1,5) valid, CIN -> 10: 3x float2 per ci row feeds both outputs
#define DECLA(i) float a0_##i = 0.f, a1_##i = 0.f;
  REP10(DECLA)
#undef DECLA
  const float* __restrict__ crow = inb + o * 1000 + t;
#pragma unroll
  for (int ci = 0; ci < CIN; ++ci) {
    const float2 x0 = *reinterpret_cast<const float2*>(crow + ci * 2000);
    const float2 x1 = *reinterpret_cast<const float2*>(crow + ci * 2000 + 2);
    const float2 x2 = *reinterpret_cast<const float2*>(crow + ci * 2000 + 4);
#define CONVK(k) {                                                             \
    const float k0 = ck[(0 * CIN + ci) * 10 + k];                              \
    const float k1 = ck[(1 * CIN + ci) * 10 + k];                              \
    const float k2 = ck[(2 * CIN + ci) * 10 + k];                              \
    const float k3 = ck[(3 * CIN + ci) * 10 + k];                              \
    const float k4 = ck[(4 * CIN + ci) * 10 + k];                              \
    a0_##k += x0.x*k0 + x0.y*k1 + x1.x*k2 + x1.y*k3 + x2.x*k4;                 \
    a1_##k += x0.y*k0 + x1.x*k1 + x1.y*k2 + x2.x*k3 + x2.y*k4; }
    REP10(CONVK)
#undef CONVK
  }

  const float r0 = __builtin_amdgcn_rcpf(sum0);
  const float r1 = __builtin_amdgcn_rcpf(sum1);

  float* __restrict__ ob = outp + (size_t)blockIdx.z * 20000 + o * 1000 + t;
#define STO(i) { const float sc_ = scale[i], sh_ = shift2[i];                  \
    float b0 = a0_##i * sc_ + sh_; b0 = fmaxf(b0, 0.2f * b0);                  \
    float b1 = a1_##i * sc_ + sh_; b1 = fmaxf(b1, 0.2f * b1);                  \
    *reinterpret_cast<float2*>(ob + i * 2000) =                                \
        make_float2(b0 * e##i##0 * r0, b1 * e##i##1 * r1); }
  REP10(STO)
#undef STO
}

// ---------------------------------------------------------------------------
// final_kernel: conv4 (2,1) -> lrelu -> dot(dns_w^T) -> block reduce.
// 2 t per thread per iteration; live set ~50 floats.
// ---------------------------------------------------------------------------
__global__ __launch_bounds__(256) void final_kernel(
    const float* __restrict__ h3, const float* __restrict__ c4k,
    const float* __restrict__ c4b, const float* __restrict__ dnswT,
    const float* __restrict__ dnsb, float* __restrict__ outp, int b0)
{
  __shared__ float red[4];
  const int tid = threadIdx.x;
  const float* __restrict__ hb = h3 + (size_t)blockIdx.x * 20000;
  float partial = 0.f;
#pragma unroll 1
  for (int t = 2 * tid; t < 988; t += 512) {
#define LOADH(i)                                                               \
    const float2 xa##i = *reinterpret_cast<const float2*>(hb + i*2000 + t);    \
    const float2 xb##i = *reinterpret_cast<const float2*>(hb + i*2000 + 1000 + t);
    REP10(LOADH)
#undef LOADH
    float d0 = 0.f, d1 = 0.f;
#pragma unroll 4
    for (int cc = 0; cc < 20; ++cc) {
      const float bias = c4b[cc];
      float a0 = bias, a1 = bias;
#define FMA4(i) { const float wA = c4k[i*20 + cc], wB = c4k[(10+i)*20 + cc];   \
      a0 += xa##i.x * wA + xb##i.x * wB; a1 += xa##i.y * wA + xb##i.y * wB; }
      REP10(FMA4)
#undef FMA4
      a0 = fmaxf(a0, 0.2f * a0); a1 = fmaxf(a1, 0.2f * a1);
      const float2 dT =
          *reinterpret_cast<const float2*>(dnswT + cc * 988 + t);
      d0 += a0 * dT.x; d1 += a1 * dT.y;
    }
    partial += d0 + d1;
  }
#pragma unroll
  for (int off = 32; off > 0; off >>= 1)
    partial += __shfl_down(partial, off, 64);
  if ((tid & 63) == 0) red[tid >> 6] = partial;
  __syncthreads();
  if (tid == 0)
    outp[b0 + blockIdx.x] = red[0] + red[1] + red[2] + red[3] + dnsb[0];
}

extern "C" void kernel_launch(void* const* d_in, const int* in_sizes, int n_in,
                              void* d_out, int out_size, void* d_ws, size_t ws_size,
                              hipStream_t stream) {
  const float* p[35];
  for (int i = 0; i < 35; ++i) p[i] = (const float*)d_in[i];
  const int B = in_sizes[0] / 2000;

  // ws layout: consts[256] | dnswT[19760] | hA | hB   (floats, 16B-aligned)
  float* consts = (float*)d_ws;
  float* dnswT  = consts + 256;
  float* hA     = consts + 20016;
  const size_t avail = ws_size - 20016u * 4u;
  int CH = 1024;
  if (CH > B) CH = B;
  while ((size_t)CH * 160000ull > avail && CH > 1) CH >>= 1;
  float* hB = hA + (size_t)CH * 20000;

  prep_kernel<<<dim3(1), dim3(64), 0, stream>>>(
      p[9], p[10], p[11], p[12], p[2], p[25], p[26],
      p[13], p[14], p[15], p[16], p[4], p[29], p[30],
      p[17], p[18], p[19], p[20], p[6], p[33], p[34],
      consts);
  transpose_dnsw<<<dim3(20), dim3(256), 0, stream>>>(p[21], dnswT);

  for (int b0 = 0; b0 < B; b0 += CH) {
    const int cc = (B - b0 < CH) ? (B - b0) : CH;
    // stage1: x -> hA (Tout=996)
    stage_kernel<1><<<dim3(4, 2, cc), dim3(128), 0, stream>>>(
        p[0] + (size_t)b0 * 2000, hA, 996, p[1], p[23], p[24], consts);
    // stage2: hA -> hB (Tout=992)
    stage_kernel<10><<<dim3(4, 2, cc), dim3(128), 0, stream>>>(
        hA, hB, 992, p[3], p[27], p[28], consts + 80);
    // stage3: hB -> hA (Tout=988)
    stage_kernel<10><<<dim3(4, 2, cc), dim3(128), 0, stream>>>(
        hB, hA, 988, p[5], p[31], p[32], consts + 160);
    // conv4 + dense head
    final_kernel<<<dim3(cc), dim3(256), 0, stream>>>(
        hA, p[7], p[8], dnswT, p[22], (float*)d_out, b0);
  }
}

// Round 11
// 298.951 us; speedup vs baseline: 1.0928x; 1.0928x over previous
//
#include <hip/hip_runtime.h>

#define REP10(X) X(0) X(1) X(2) X(3) X(4) X(5) X(6) X(7) X(8) X(9)
#define REP5(X)  X(0) X(1) X(2) X(3) X(4)

typedef __attribute__((ext_vector_type(2))) float v2;

// ---------------------------------------------------------------------------
// prep_kernel: per stage (stride 512 in consts):
// [0..10) scale | [10..20) shift2 (bn+conv-bias folded) | [20..70) adw2 |
// [70..80) adb2 (adw/adb pre-scaled by log2e) | [80..100) abp[o*10+i] |
// [100..100+2*CIN*2*10) aKp[((h*CIN+ci)*2+o)*10 + i]  (head-contiguous)
// Channel/head pairs are contiguous everywhere -> float2 (v_pk_fma_f32) math.
// ---------------------------------------------------------------------------
__device__ __forceinline__ void fold_stage(
    float* dst, const float* g, const float* be, const float* mn,
    const float* vr, const float* cb, const float* adw, const float* adb,
    const float* aK, const float* ab, int CIN)
{
  const int tid = threadIdx.x;
  if (tid < 10) {
    const float sc = g[tid] * rsqrtf(vr[tid] + 1e-3f);
    dst[tid]      = sc;
    dst[10 + tid] = (cb[tid] - mn[tid]) * sc + be[tid];
    dst[70 + tid] = adb[tid] * 1.44269504088896340736f;
  }
  if (tid >= 10 && tid < 60)
    dst[10 + tid] = adw[tid - 10] * 1.44269504088896340736f;
  if (tid < 20)  // abp[o*10+i] = ab[i*2+o]
    dst[80 + tid] = ab[(tid % 10) * 2 + tid / 10];
  const int n = 2 * CIN * 2 * 10;
  for (int idx = tid; idx < n; idx += 64) {
    const int i  = idx % 10;
    const int r  = idx / 10;
    const int o  = r % 2;
    const int r2 = r / 2;
    const int ci = r2 % CIN;
    const int h  = r2 / CIN;
    dst[100 + idx] = aK[((i * 2 + h) * CIN + ci) * 2 + o];
  }
}

__global__ void prep_kernel(
    const float* g1, const float* be1, const float* m1, const float* v1,
    const float* cb1, const float* a1dw, const float* a1db,
    const float* a1K, const float* a1b,
    const float* g2, const float* be2, const float* m2, const float* v2_,
    const float* cb2, const float* a2dw, const float* a2db,
    const float* a2K, const float* a2b,
    const float* g3, const float* be3, const float* m3, const float* v3,
    const float* cb3, const float* a3dw, const float* a3db,
    const float* a3K, const float* a3b,
    float* consts)
{
  fold_stage(consts,        g1, be1, m1, v1,  cb1, a1dw, a1db, a1K, a1b, 1);
  fold_stage(consts + 512,  g2, be2, m2, v2_, cb2, a2dw, a2db, a2K, a2b, 10);
  fold_stage(consts + 1024, g3, be3, m3, v3,  cb3, a3dw, a3db, a3K, a3b, 10);
}

// dnswT[cc][t] = dnsw[t*20+cc]
__global__ void transpose_dnsw(const float* __restrict__ dnsw,
                               float* __restrict__ dnswT)
{
  const int cc = blockIdx.x;
  for (int t = threadIdx.x; t < 988; t += 256)
    dnswT[cc * 988 + t] = dnsw[t * 20 + cc];
}

// ---------------------------------------------------------------------------
// stage_kernel: EXACT R8 structure (1 output/thread, 256-thr block, tile 256,
// LDS = smm only) -- the only shape that avoided both the scratch monster
// (R1-5, R9) and the 2-wide VALU bloat (R10). New: channel-PAIR float2 math
// (packed fp32 FMA candidate); per-group accumulators stay 5 regs.
// in : [bc][CIN][2][1000] ; out : [bc][10][2][1000]
// ---------------------------------------------------------------------------
template <int CIN>
__global__ __launch_bounds__(256) void stage_kernel(
    const float* __restrict__ in, float* __restrict__ outp, int Tout,
    const float* __restrict__ ck, const float* __restrict__ cst)
{
  __shared__ float smm[10][264];
  const int tid = threadIdx.x;
  const int o   = blockIdx.y;
  const int t0  = blockIdx.x * 256;
  const int Tin = Tout + 4;
  const float* __restrict__ inb = in + (size_t)blockIdx.z * (CIN * 2000);

  const float* __restrict__ scale  = cst;
  const float* __restrict__ shift2 = cst + 10;
  const float* __restrict__ adw2   = cst + 20;
  const float* __restrict__ adb2   = cst + 70;
  const float* __restrict__ abp    = cst + 80;
  const float* __restrict__ aKp    = cst + 100;

  // ---- Phase A: einsum m (head-pairs packed) -> smm
  for (int lt = tid; lt < 260; lt += 256) {
    const int t = t0 + lt;
    if (t < Tin) {
#define DECLM(p) v2 mp##p = *reinterpret_cast<const v2*>(abp + o * 10 + 2 * p);
      REP5(DECLM)
#undef DECLM
#pragma unroll
      for (int h = 0; h < 2; ++h)
#pragma unroll
        for (int ci = 0; ci < CIN; ++ci) {
          const float xin = inb[(ci * 2 + h) * 1000 + t];
          const float* kb = aKp + ((h * CIN + ci) * 2 + o) * 10;
#define FMAM(p) mp##p += xin * *reinterpret_cast<const v2*>(kb + 2 * p);
          REP5(FMAM)
#undef FMAM
        }
#define STM(p) smm[2 * p][lt] = mp##p.x; smm[2 * p + 1][lt] = mp##p.y;
      REP5(STM)
#undef STM
    }
  }
  __syncthreads();

  // ---- Phase B: 1 output/thread (no barriers below -> early-out safe)
  const int tt = t0 + tid;
  if (tt >= Tout) return;

  // depthwise logits, channel-pairs packed
#define DECLY(p) v2 yp##p = *reinterpret_cast<const v2*>(adb2 + 2 * p);
  REP5(DECLY)
#undef DECLY
#pragma unroll
  for (int w = 0; w < 5; ++w) {
    const float* aw = adw2 + w * 10;
#define FMAY(p) { const v2 sv = {smm[2 * p][tid + w], smm[2 * p + 1][tid + w]}; \
    yp##p += sv * *reinterpret_cast<const v2*>(aw + 2 * p); }
    REP5(FMAY)
#undef FMAY
  }

  // conv (1,5) valid, CIN -> 10, channel-pairs packed; x from global (L1-hot)
#define DECLA(p) v2 ap##p = {0.f, 0.f};
  REP5(DECLA)
#undef DECLA
  const float* __restrict__ cinb = inb + o * 1000 + tt;
#pragma unroll
  for (int w = 0; w < 5; ++w)
#pragma unroll
    for (int ci = 0; ci < CIN; ++ci) {
      const float xin = cinb[ci * 2000 + w];
      const float* kb = ck + (w * CIN + ci) * 10;
#define FMAC(p) ap##p += xin * *reinterpret_cast<const v2*>(kb + 2 * p);
      REP5(FMAC)
#undef FMAC
    }

  // softmax over 10 heads via native exp2 (scalar epilogue, R8-validated)
  const float y0 = yp0.x, y1 = yp0.y, y2 = yp1.x, y3 = yp1.y, y4 = yp2.x,
              y5 = yp2.y, y6 = yp3.x, y7 = yp3.y, y8 = yp4.x, y9 = yp4.y;
  float mx = y0;
  mx = fmaxf(mx, y1); mx = fmaxf(mx, y2); mx = fmaxf(mx, y3);
  mx = fmaxf(mx, y4); mx = fmaxf(mx, y5); mx = fmaxf(mx, y6);
  mx = fmaxf(mx, y7); mx = fmaxf(mx, y8); mx = fmaxf(mx, y9);
#define DECLE(i) const float e##i = exp2f(y##i - mx);
  REP10(DECLE)
#undef DECLE
  const float sm  = e0 + e1 + e2 + e3 + e4 + e5 + e6 + e7 + e8 + e9;
  const float inv = __builtin_amdgcn_rcpf(sm);

  const float a0 = ap0.x, a1 = ap0.y, a2 = ap1.x, a3 = ap1.y, a4 = ap2.x,
              a5 = ap2.y, a6 = ap3.x, a7 = ap3.y, a8 = ap4.x, a9 = ap4.y;
  float* __restrict__ ob = outp + (size_t)blockIdx.z * 20000 + o * 1000 + tt;
#define STO(i) { float bv = a##i * scale[i] + shift2[i];                       \
    bv = fmaxf(bv, 0.2f * bv);                                                 \
    ob[i * 2000] = bv * e##i * inv; }
  REP10(STO)
#undef STO
}

// ---------------------------------------------------------------------------
// final_kernel: conv4 (2,1) -> lrelu -> dot(dns_w^T) -> block reduce.
// ---------------------------------------------------------------------------
__global__ __launch_bounds__(256) void final_kernel(
    const float* __restrict__ h3, const float* __restrict__ c4k,
    const float* __restrict__ c4b, const float* __restrict__ dnswT,
    const float* __restrict__ dnsb, float* __restrict__ outp, int b0)
{
  __shared__ float red[4];
  const int tid = threadIdx.x;
  const float* __restrict__ hb = h3 + (size_t)blockIdx.x * 20000;
  float partial = 0.f;
#pragma unroll 1
  for (int t = 2 * tid; t < 988; t += 512) {
#define LOADH(i)                                                               \
    const float2 xa##i = *reinterpret_cast<const float2*>(hb + i*2000 + t);    \
    const float2 xb##i = *reinterpret_cast<const float2*>(hb + i*2000 + 1000 + t);
    REP10(LOADH)
#undef LOADH
    float d0 = 0.f, d1 = 0.f;
#pragma unroll 4
    for (int cc = 0; cc < 20; ++cc) {
      const float bias = c4b[cc];
      float a0 = bias, a1 = bias;
#define FMA4(i) { const float wA = c4k[i*20 + cc], wB = c4k[(10+i)*20 + cc];   \
      a0 += xa##i.x * wA + xb##i.x * wB; a1 += xa##i.y * wA + xb##i.y * wB; }
      REP10(FMA4)
#undef FMA4
      a0 = fmaxf(a0, 0.2f * a0); a1 = fmaxf(a1, 0.2f * a1);
      const float2 dT = *reinterpret_cast<const float2*>(dnswT + cc * 988 + t);
      d0 += a0 * dT.x; d1 += a1 * dT.y;
    }
    partial += d0 + d1;
  }
#pragma unroll
  for (int off = 32; off > 0; off >>= 1)
    partial += __shfl_down(partial, off, 64);
  if ((tid & 63) == 0) red[tid >> 6] = partial;
  __syncthreads();
  if (tid == 0)
    outp[b0 + blockIdx.x] = red[0] + red[1] + red[2] + red[3] + dnsb[0];
}

extern "C" void kernel_launch(void* const* d_in, const int* in_sizes, int n_in,
                              void* d_out, int out_size, void* d_ws, size_t ws_size,
                              hipStream_t stream) {
  const float* p[35];
  for (int i = 0; i < 35; ++i) p[i] = (const float*)d_in[i];
  const int B = in_sizes[0] / 2000;

  // ws: consts[1536] | dnswT[19760] | hA | hB
  float* consts = (float*)d_ws;
  float* dnswT  = consts + 1536;
  float* hA     = consts + 21296;
  const size_t avail = ws_size - 21296u * 4u;
  // CH=256: ping-pong buffers 20 MB each -> inter-stage traffic stays
  // L2/L3-resident (R8's CH=1024 showed 104 MB HBM FETCH = L3 thrash);
  // grid (4,2,256)=2048 blocks = 8 blocks/CU, exactly fills the GPU.
  int CH = 256;
  if (CH > B) CH = B;
  while ((size_t)CH * 160000ull > avail && CH > 1) CH >>= 1;
  float* hB = hA + (size_t)CH * 20000;

  prep_kernel<<<dim3(1), dim3(64), 0, stream>>>(
      p[9], p[10], p[11], p[12], p[2], p[25], p[26], p[23], p[24],
      p[13], p[14], p[15], p[16], p[4], p[29], p[30], p[27], p[28],
      p[17], p[18], p[19], p[20], p[6], p[33], p[34], p[31], p[32],
      consts);
  transpose_dnsw<<<dim3(20), dim3(256), 0, stream>>>(p[21], dnswT);

  for (int b0 = 0; b0 < B; b0 += CH) {
    const int cc = (B - b0 < CH) ? (B - b0) : CH;
    const dim3 blk(256);
    // stage1: x -> hA (Tout=996)
    stage_kernel<1><<<dim3(4, 2, cc), blk, 0, stream>>>(
        p[0] + (size_t)b0 * 2000, hA, 996, p[1], consts);
    // stage2: hA -> hB (Tout=992)
    stage_kernel<10><<<dim3(4, 2, cc), blk, 0, stream>>>(
        hA, hB, 992, p[3], consts + 512);
    // stage3: hB -> hA (Tout=988)
    stage_kernel<10><<<dim3(4, 2, cc), blk, 0, stream>>>(
        hB, hA, 988, p[5], consts + 1024);
    // conv4 + dense head
    final_kernel<<<dim3(cc), blk, 0, stream>>>(
        hA, p[7], p[8], dnswT, p[22], (float*)d_out, b0);
  }
}

// Round 12
// 186.416 us; speedup vs baseline: 1.7526x; 1.6037x over previous
//
#include <hip/hip_runtime.h>

#define REP10(X) X(0) X(1) X(2) X(3) X(4) X(5) X(6) X(7) X(8) X(9)
#define REP5(X)  X(0) X(1) X(2) X(3) X(4)

typedef __attribute__((ext_vector_type(2))) float v2;

// ---------------------------------------------------------------------------
// prep_kernel: per stage (stride 512 in consts):
// [0..10) scale | [10..20) shift2 (bn+conv-bias folded) | [20..70) adw2 |
// [70..80) adb2 (adw/adb pre-scaled by log2e) | [80..100) abp[o*10+i] |
// [100..100+2*CIN*2*10) aKp[((h*CIN+ci)*2+o)*10 + i]  (head-contiguous)
// Channel/head pairs contiguous everywhere -> float2 (v_pk_fma_f32 candidate).
// ---------------------------------------------------------------------------
__device__ __forceinline__ void fold_stage(
    float* dst, const float* g, const float* be, const float* mn,
    const float* vr, const float* cb, const float* adw, const float* adb,
    const float* aK, const float* ab, int CIN)
{
  const int tid = threadIdx.x;
  if (tid < 10) {
    const float sc = g[tid] * rsqrtf(vr[tid] + 1e-3f);
    dst[tid]      = sc;
    dst[10 + tid] = (cb[tid] - mn[tid]) * sc + be[tid];
    dst[70 + tid] = adb[tid] * 1.44269504088896340736f;
  }
  if (tid >= 10 && tid < 60)
    dst[10 + tid] = adw[tid - 10] * 1.44269504088896340736f;
  if (tid < 20)  // abp[o*10+i] = ab[i*2+o]
    dst[80 + tid] = ab[(tid % 10) * 2 + tid / 10];
  const int n = 2 * CIN * 2 * 10;
  for (int idx = tid; idx < n; idx += 64) {
    const int i  = idx % 10;
    const int r  = idx / 10;
    const int o  = r % 2;
    const int r2 = r / 2;
    const int ci = r2 % CIN;
    const int h  = r2 / CIN;
    dst[100 + idx] = aK[((i * 2 + h) * CIN + ci) * 2 + o];
  }
}

__global__ void prep_kernel(
    const float* g1, const float* be1, const float* m1, const float* v1,
    const float* cb1, const float* a1dw, const float* a1db,
    const float* a1K, const float* a1b,
    const float* g2, const float* be2, const float* m2, const float* v2_,
    const float* cb2, const float* a2dw, const float* a2db,
    const float* a2K, const float* a2b,
    const float* g3, const float* be3, const float* m3, const float* v3,
    const float* cb3, const float* a3dw, const float* a3db,
    const float* a3K, const float* a3b,
    float* consts)
{
  fold_stage(consts,        g1, be1, m1, v1,  cb1, a1dw, a1db, a1K, a1b, 1);
  fold_stage(consts + 512,  g2, be2, m2, v2_, cb2, a2dw, a2db, a2K, a2b, 10);
  fold_stage(consts + 1024, g3, be3, m3, v3,  cb3, a3dw, a3db, a3K, a3b, 10);
}

// dnswT[cc][t] = dnsw[t*20+cc]
__global__ void transpose_dnsw(const float* __restrict__ dnsw,
                               float* __restrict__ dnswT)
{
  const int cc = blockIdx.x;
  for (int t = threadIdx.x; t < 988; t += 256)
    dnswT[cc * 988 + t] = dnsw[t * 20 + cc];
}

// ---------------------------------------------------------------------------
// stage_kernel: R8 structure (1 output/thread, 256-thr block, tile 256,
// LDS = smm only) + channel-pair float2 math. R11 bundled this with CH=256
// chunking, which regressed on launch bubbles and masked the counters; this
// round isolates the packing at CH=1024 (single chunk, 6 launches).
// in : [bc][CIN][2][1000] ; out : [bc][10][2][1000]
// ---------------------------------------------------------------------------
template <int CIN>
__global__ __launch_bounds__(256) void stage_kernel(
    const float* __restrict__ in, float* __restrict__ outp, int Tout,
    const float* __restrict__ ck, const float* __restrict__ cst)
{
  __shared__ float smm[10][264];
  const int tid = threadIdx.x;
  const int o   = blockIdx.y;
  const int t0  = blockIdx.x * 256;
  const int Tin = Tout + 4;
  const float* __restrict__ inb = in + (size_t)blockIdx.z * (CIN * 2000);

  const float* __restrict__ scale  = cst;
  const float* __restrict__ shift2 = cst + 10;
  const float* __restrict__ adw2   = cst + 20;
  const float* __restrict__ adb2   = cst + 70;
  const float* __restrict__ abp    = cst + 80;
  const float* __restrict__ aKp    = cst + 100;

  // ---- Phase A: einsum m (head-pairs packed) -> smm
  for (int lt = tid; lt < 260; lt += 256) {
    const int t = t0 + lt;
    if (t < Tin) {
#define DECLM(p) v2 mp##p = *reinterpret_cast<const v2*>(abp + o * 10 + 2 * p);
      REP5(DECLM)
#undef DECLM
#pragma unroll
      for (int h = 0; h < 2; ++h)
#pragma unroll
        for (int ci = 0; ci < CIN; ++ci) {
          const float xin = inb[(ci * 2 + h) * 1000 + t];
          const float* kb = aKp + ((h * CIN + ci) * 2 + o) * 10;
#define FMAM(p) mp##p += xin * *reinterpret_cast<const v2*>(kb + 2 * p);
          REP5(FMAM)
#undef FMAM
        }
#define STM(p) smm[2 * p][lt] = mp##p.x; smm[2 * p + 1][lt] = mp##p.y;
      REP5(STM)
#undef STM
    }
  }
  __syncthreads();

  // ---- Phase B: 1 output/thread (no barriers below -> early-out safe)
  const int tt = t0 + tid;
  if (tt >= Tout) return;

  // depthwise logits, channel-pairs packed
#define DECLY(p) v2 yp##p = *reinterpret_cast<const v2*>(adb2 + 2 * p);
  REP5(DECLY)
#undef DECLY
#pragma unroll
  for (int w = 0; w < 5; ++w) {
    const float* aw = adw2 + w * 10;
#define FMAY(p) { const v2 sv = {smm[2 * p][tid + w], smm[2 * p + 1][tid + w]}; \
    yp##p += sv * *reinterpret_cast<const v2*>(aw + 2 * p); }
    REP5(FMAY)
#undef FMAY
  }

  // conv (1,5) valid, CIN -> 10, channel-pairs packed; x from global (L1-hot)
#define DECLA(p) v2 ap##p = {0.f, 0.f};
  REP5(DECLA)
#undef DECLA
  const float* __restrict__ cinb = inb + o * 1000 + tt;
#pragma unroll
  for (int w = 0; w < 5; ++w)
#pragma unroll
    for (int ci = 0; ci < CIN; ++ci) {
      const float xin = cinb[ci * 2000 + w];
      const float* kb = ck + (w * CIN + ci) * 10;
#define FMAC(p) ap##p += xin * *reinterpret_cast<const v2*>(kb + 2 * p);
      REP5(FMAC)
#undef FMAC
    }

  // softmax over 10 heads via native exp2 (scalar epilogue, R8-validated)
  const float y0 = yp0.x, y1 = yp0.y, y2 = yp1.x, y3 = yp1.y, y4 = yp2.x,
              y5 = yp2.y, y6 = yp3.x, y7 = yp3.y, y8 = yp4.x, y9 = yp4.y;
  float mx = y0;
  mx = fmaxf(mx, y1); mx = fmaxf(mx, y2); mx = fmaxf(mx, y3);
  mx = fmaxf(mx, y4); mx = fmaxf(mx, y5); mx = fmaxf(mx, y6);
  mx = fmaxf(mx, y7); mx = fmaxf(mx, y8); mx = fmaxf(mx, y9);
#define DECLE(i) const float e##i = exp2f(y##i - mx);
  REP10(DECLE)
#undef DECLE
  const float sm  = e0 + e1 + e2 + e3 + e4 + e5 + e6 + e7 + e8 + e9;
  const float inv = __builtin_amdgcn_rcpf(sm);

  const float a0 = ap0.x, a1 = ap0.y, a2 = ap1.x, a3 = ap1.y, a4 = ap2.x,
              a5 = ap2.y, a6 = ap3.x, a7 = ap3.y, a8 = ap4.x, a9 = ap4.y;
  float* __restrict__ ob = outp + (size_t)blockIdx.z * 20000 + o * 1000 + tt;
#define STO(i) { float bv = a##i * scale[i] + shift2[i];                       \
    bv = fmaxf(bv, 0.2f * bv);                                                 \
    ob[i * 2000] = bv * e##i * inv; }
  REP10(STO)
#undef STO
}

// ---------------------------------------------------------------------------
// final_kernel: conv4 (2,1) -> lrelu -> dot(dns_w^T) -> block reduce.
// ---------------------------------------------------------------------------
__global__ __launch_bounds__(256) void final_kernel(
    const float* __restrict__ h3, const float* __restrict__ c4k,
    const float* __restrict__ c4b, const float* __restrict__ dnswT,
    const float* __restrict__ dnsb, float* __restrict__ outp, int b0)
{
  __shared__ float red[4];
  const int tid = threadIdx.x;
  const float* __restrict__ hb = h3 + (size_t)blockIdx.x * 20000;
  float partial = 0.f;
#pragma unroll 1
  for (int t = 2 * tid; t < 988; t += 512) {
#define LOADH(i)                                                               \
    const float2 xa##i = *reinterpret_cast<const float2*>(hb + i*2000 + t);    \
    const float2 xb##i = *reinterpret_cast<const float2*>(hb + i*2000 + 1000 + t);
    REP10(LOADH)
#undef LOADH
    float d0 = 0.f, d1 = 0.f;
#pragma unroll 4
    for (int cc = 0; cc < 20; ++cc) {
      const float bias = c4b[cc];
      float a0 = bias, a1 = bias;
#define FMA4(i) { const float wA = c4k[i*20 + cc], wB = c4k[(10+i)*20 + cc];   \
      a0 += xa##i.x * wA + xb##i.x * wB; a1 += xa##i.y * wA + xb##i.y * wB; }
      REP10(FMA4)
#undef FMA4
      a0 = fmaxf(a0, 0.2f * a0); a1 = fmaxf(a1, 0.2f * a1);
      const float2 dT = *reinterpret_cast<const float2*>(dnswT + cc * 988 + t);
      d0 += a0 * dT.x; d1 += a1 * dT.y;
    }
    partial += d0 + d1;
  }
#pragma unroll
  for (int off = 32; off > 0; off >>= 1)
    partial += __shfl_down(partial, off, 64);
  if ((tid & 63) == 0) red[tid >> 6] = partial;
  __syncthreads();
  if (tid == 0)
    outp[b0 + blockIdx.x] = red[0] + red[1] + red[2] + red[3] + dnsb[0];
}

extern "C" void kernel_launch(void* const* d_in, const int* in_sizes, int n_in,
                              void* d_out, int out_size, void* d_ws, size_t ws_size,
                              hipStream_t stream) {
  const float* p[35];
  for (int i = 0; i < 35; ++i) p[i] = (const float*)d_in[i];
  const int B = in_sizes[0] / 2000;

  // ws: consts[1536] | dnswT[19760] | hA | hB
  float* consts = (float*)d_ws;
  float* dnswT  = consts + 1536;
  float* hA     = consts + 21296;
  const size_t avail = ws_size - 21296u * 4u;
  // CH=1024: single chunk, 6 launches total. R11's CH=256 split into 4
  // serial launch waves (18 kernels) and regressed ~80 µs on launch bubbles.
  int CH = 1024;
  if (CH > B) CH = B;
  while ((size_t)CH * 160000ull > avail && CH > 1) CH >>= 1;
  float* hB = hA + (size_t)CH * 20000;

  prep_kernel<<<dim3(1), dim3(64), 0, stream>>>(
      p[9], p[10], p[11], p[12], p[2], p[25], p[26], p[23], p[24],
      p[13], p[14], p[15], p[16], p[4], p[29], p[30], p[27], p[28],
      p[17], p[18], p[19], p[20], p[6], p[33], p[34], p[31], p[32],
      consts);
  transpose_dnsw<<<dim3(20), dim3(256), 0, stream>>>(p[21], dnswT);

  for (int b0 = 0; b0 < B; b0 += CH) {
    const int cc = (B - b0 < CH) ? (B - b0) : CH;
    const dim3 blk(256);
    // stage1: x -> hA (Tout=996)
    stage_kernel<1><<<dim3(4, 2, cc), blk, 0, stream>>>(
        p[0] + (size_t)b0 * 2000, hA, 996, p[1], consts);
    // stage2: hA -> hB (Tout=992)
    stage_kernel<10><<<dim3(4, 2, cc), blk, 0, stream>>>(
        hA, hB, 992, p[3], consts + 512);
    // stage3: hB -> hA (Tout=988)
    stage_kernel<10><<<dim3(4, 2, cc), blk, 0, stream>>>(
        hB, hA, 988, p[5], consts + 1024);
    // conv4 + dense head
    final_kernel<<<dim3(cc), blk, 0, stream>>>(
        hA, p[7], p[8], dnswT, p[22], (float*)d_out, b0);
  }
}

// Round 13
// 179.650 us; speedup vs baseline: 1.8186x; 1.0377x over previous
//
#include <hip/hip_runtime.h>

#define REP10(X) X(0) X(1) X(2) X(3) X(4) X(5) X(6) X(7) X(8) X(9)
#define REP5(X)  X(0) X(1) X(2) X(3) X(4)

typedef __attribute__((ext_vector_type(2))) float v2;

// ---------------------------------------------------------------------------
// prep_kernel: per stage (stride 512 in consts):
// [0..10) scale | [10..20) shift2 (bn+conv-bias folded) | [20..70) adw2 |
// [70..80) adb2 (adw/adb pre-scaled by log2e) | [80..100) abp[o*10+i] |
// [100..100+2*CIN*2*10) aKp[((h*CIN+ci)*2+o)*10 + i]  (head-contiguous)
// ---------------------------------------------------------------------------
__device__ __forceinline__ void fold_stage(
    float* dst, const float* g, const float* be, const float* mn,
    const float* vr, const float* cb, const float* adw, const float* adb,
    const float* aK, const float* ab, int CIN)
{
  const int tid = threadIdx.x;
  if (tid < 10) {
    const float sc = g[tid] * rsqrtf(vr[tid] + 1e-3f);
    dst[tid]      = sc;
    dst[10 + tid] = (cb[tid] - mn[tid]) * sc + be[tid];
    dst[70 + tid] = adb[tid] * 1.44269504088896340736f;
  }
  if (tid >= 10 && tid < 60)
    dst[10 + tid] = adw[tid - 10] * 1.44269504088896340736f;
  if (tid < 20)  // abp[o*10+i] = ab[i*2+o]
    dst[80 + tid] = ab[(tid % 10) * 2 + tid / 10];
  const int n = 2 * CIN * 2 * 10;
  for (int idx = tid; idx < n; idx += 64) {
    const int i  = idx % 10;
    const int r  = idx / 10;
    const int o  = r % 2;
    const int r2 = r / 2;
    const int ci = r2 % CIN;
    const int h  = r2 / CIN;
    dst[100 + idx] = aK[((i * 2 + h) * CIN + ci) * 2 + o];
  }
}

__global__ void prep_kernel(
    const float* g1, const float* be1, const float* m1, const float* v1,
    const float* cb1, const float* a1dw, const float* a1db,
    const float* a1K, const float* a1b,
    const float* g2, const float* be2, const float* m2, const float* v2_,
    const float* cb2, const float* a2dw, const float* a2db,
    const float* a2K, const float* a2b,
    const float* g3, const float* be3, const float* m3, const float* v3,
    const float* cb3, const float* a3dw, const float* a3db,
    const float* a3K, const float* a3b,
    float* consts)
{
  fold_stage(consts,        g1, be1, m1, v1,  cb1, a1dw, a1db, a1K, a1b, 1);
  fold_stage(consts + 512,  g2, be2, m2, v2_, cb2, a2dw, a2db, a2K, a2b, 10);
  fold_stage(consts + 1024, g3, be3, m3, v3,  cb3, a3dw, a3db, a3K, a3b, 10);
}

// dnswT[cc][t] = dnsw[t*20+cc]
__global__ void transpose_dnsw(const float* __restrict__ dnsw,
                               float* __restrict__ dnswT)
{
  const int cc = blockIdx.x;
  for (int t = threadIdx.x; t < 988; t += 256)
    dnswT[cc * 988 + t] = dnsw[t * 20 + cc];
}

// ---------------------------------------------------------------------------
// stage_kernel: R12 code shape, block/tile halved to 128 (single change).
// R12 anomaly: all stages ~66us regardless of FMA/mem-op count => limiter is
// the common Phase-B path (LDS depthwise + serial softmax) at only 16
// waves/CU => latency-bound. 128-thr blocks double co-resident blocks/CU
// (8->16 by thread cap) and halve barrier width for finer interleave.
// in : [bc][CIN][2][1000] ; out : [bc][10][2][1000]
// ---------------------------------------------------------------------------
template <int CIN>
__global__ __launch_bounds__(128) void stage_kernel(
    const float* __restrict__ in, float* __restrict__ outp, int Tout,
    const float* __restrict__ ck, const float* __restrict__ cst)
{
  __shared__ float smm[10][136];
  const int tid = threadIdx.x;      // 0..127
  const int o   = blockIdx.y;
  const int t0  = blockIdx.x * 128;
  const int Tin = Tout + 4;
  const float* __restrict__ inb = in + (size_t)blockIdx.z * (CIN * 2000);

  const float* __restrict__ scale  = cst;
  const float* __restrict__ shift2 = cst + 10;
  const float* __restrict__ adw2   = cst + 20;
  const float* __restrict__ adb2   = cst + 70;
  const float* __restrict__ abp    = cst + 80;
  const float* __restrict__ aKp    = cst + 100;

  // ---- Phase A: einsum m (head-pairs packed) -> smm, positions [t0,t0+132)
  for (int lt = tid; lt < 132; lt += 128) {
    const int t = t0 + lt;
    if (t < Tin) {
#define DECLM(p) v2 mp##p = *reinterpret_cast<const v2*>(abp + o * 10 + 2 * p);
      REP5(DECLM)
#undef DECLM
#pragma unroll
      for (int h = 0; h < 2; ++h)
#pragma unroll
        for (int ci = 0; ci < CIN; ++ci) {
          const float xin = inb[(ci * 2 + h) * 1000 + t];
          const float* kb = aKp + ((h * CIN + ci) * 2 + o) * 10;
#define FMAM(p) mp##p += xin * *reinterpret_cast<const v2*>(kb + 2 * p);
          REP5(FMAM)
#undef FMAM
        }
#define STM(p) smm[2 * p][lt] = mp##p.x; smm[2 * p + 1][lt] = mp##p.y;
      REP5(STM)
#undef STM
    }
  }
  __syncthreads();

  // ---- Phase B: 1 output/thread (no barriers below -> early-out safe)
  const int tt = t0 + tid;
  if (tt >= Tout) return;

  // depthwise logits, channel-pairs packed
#define DECLY(p) v2 yp##p = *reinterpret_cast<const v2*>(adb2 + 2 * p);
  REP5(DECLY)
#undef DECLY
#pragma unroll
  for (int w = 0; w < 5; ++w) {
    const float* aw = adw2 + w * 10;
#define FMAY(p) { const v2 sv = {smm[2 * p][tid + w], smm[2 * p + 1][tid + w]}; \
    yp##p += sv * *reinterpret_cast<const v2*>(aw + 2 * p); }
    REP5(FMAY)
#undef FMAY
  }

  // conv (1,5) valid, CIN -> 10, channel-pairs packed; x from global (L1-hot)
#define DECLA(p) v2 ap##p = {0.f, 0.f};
  REP5(DECLA)
#undef DECLA
  const float* __restrict__ cinb = inb + o * 1000 + tt;
#pragma unroll
  for (int w = 0; w < 5; ++w)
#pragma unroll
    for (int ci = 0; ci < CIN; ++ci) {
      const float xin = cinb[ci * 2000 + w];
      const float* kb = ck + (w * CIN + ci) * 10;
#define FMAC(p) ap##p += xin * *reinterpret_cast<const v2*>(kb + 2 * p);
      REP5(FMAC)
#undef FMAC
    }

  // softmax over 10 heads via native exp2
  const float y0 = yp0.x, y1 = yp0.y, y2 = yp1.x, y3 = yp1.y, y4 = yp2.x,
              y5 = yp2.y, y6 = yp3.x, y7 = yp3.y, y8 = yp4.x, y9 = yp4.y;
  float mx = y0;
  mx = fmaxf(mx, y1); mx = fmaxf(mx, y2); mx = fmaxf(mx, y3);
  mx = fmaxf(mx, y4); mx = fmaxf(mx, y5); mx = fmaxf(mx, y6);
  mx = fmaxf(mx, y7); mx = fmaxf(mx, y8); mx = fmaxf(mx, y9);
#define DECLE(i) const float e##i = exp2f(y##i - mx);
  REP10(DECLE)
#undef DECLE
  const float sm  = e0 + e1 + e2 + e3 + e4 + e5 + e6 + e7 + e8 + e9;
  const float inv = __builtin_amdgcn_rcpf(sm);

  const float a0 = ap0.x, a1 = ap0.y, a2 = ap1.x, a3 = ap1.y, a4 = ap2.x,
              a5 = ap2.y, a6 = ap3.x, a7 = ap3.y, a8 = ap4.x, a9 = ap4.y;
  float* __restrict__ ob = outp + (size_t)blockIdx.z * 20000 + o * 1000 + tt;
#define STO(i) { float bv = a##i * scale[i] + shift2[i];                       \
    bv = fmaxf(bv, 0.2f * bv);                                                 \
    ob[i * 2000] = bv * e##i * inv; }
  REP10(STO)
#undef STO
}

// ---------------------------------------------------------------------------
// final_kernel: conv4 (2,1) -> lrelu -> dot(dns_w^T) -> block reduce.
// ---------------------------------------------------------------------------
__global__ __launch_bounds__(256) void final_kernel(
    const float* __restrict__ h3, const float* __restrict__ c4k,
    const float* __restrict__ c4b, const float* __restrict__ dnswT,
    const float* __restrict__ dnsb, float* __restrict__ outp, int b0)
{
  __shared__ float red[4];
  const int tid = threadIdx.x;
  const float* __restrict__ hb = h3 + (size_t)blockIdx.x * 20000;
  float partial = 0.f;
#pragma unroll 1
  for (int t = 2 * tid; t < 988; t += 512) {
#define LOADH(i)                                                               \
    const float2 xa##i = *reinterpret_cast<const float2*>(hb + i*2000 + t);    \
    const float2 xb##i = *reinterpret_cast<const float2*>(hb + i*2000 + 1000 + t);
    REP10(LOADH)
#undef LOADH
    float d0 = 0.f, d1 = 0.f;
#pragma unroll 4
    for (int cc = 0; cc < 20; ++cc) {
      const float bias = c4b[cc];
      float a0 = bias, a1 = bias;
#define FMA4(i) { const float wA = c4k[i*20 + cc], wB = c4k[(10+i)*20 + cc];   \
      a0 += xa##i.x * wA + xb##i.x * wB; a1 += xa##i.y * wA + xb##i.y * wB; }
      REP10(FMA4)
#undef FMA4
      a0 = fmaxf(a0, 0.2f * a0); a1 = fmaxf(a1, 0.2f * a1);
      const float2 dT = *reinterpret_cast<const float2*>(dnswT + cc * 988 + t);
      d0 += a0 * dT.x; d1 += a1 * dT.y;
    }
    partial += d0 + d1;
  }
#pragma unroll
  for (int off = 32; off > 0; off >>= 1)
    partial += __shfl_down(partial, off, 64);
  if ((tid & 63) == 0) red[tid >> 6] = partial;
  __syncthreads();
  if (tid == 0)
    outp[b0 + blockIdx.x] = red[0] + red[1] + red[2] + red[3] + dnsb[0];
}

extern "C" void kernel_launch(void* const* d_in, const int* in_sizes, int n_in,
                              void* d_out, int out_size, void* d_ws, size_t ws_size,
                              hipStream_t stream) {
  const float* p[35];
  for (int i = 0; i < 35; ++i) p[i] = (const float*)d_in[i];
  const int B = in_sizes[0] / 2000;

  // ws: consts[1536] | dnswT[19760] | hA | hB
  float* consts = (float*)d_ws;
  float* dnswT  = consts + 1536;
  float* hA     = consts + 21296;
  const size_t avail = ws_size - 21296u * 4u;
  int CH = 1024;
  if (CH > B) CH = B;
  while ((size_t)CH * 160000ull > avail && CH > 1) CH >>= 1;
  float* hB = hA + (size_t)CH * 20000;

  prep_kernel<<<dim3(1), dim3(64), 0, stream>>>(
      p[9], p[10], p[11], p[12], p[2], p[25], p[26], p[23], p[24],
      p[13], p[14], p[15], p[16], p[4], p[29], p[30], p[27], p[28],
      p[17], p[18], p[19], p[20], p[6], p[33], p[34], p[31], p[32],
      consts);
  transpose_dnsw<<<dim3(20), dim3(256), 0, stream>>>(p[21], dnswT);

  for (int b0 = 0; b0 < B; b0 += CH) {
    const int cc = (B - b0 < CH) ? (B - b0) : CH;
    // stage1: x -> hA (Tout=996)
    stage_kernel<1><<<dim3(8, 2, cc), dim3(128), 0, stream>>>(
        p[0] + (size_t)b0 * 2000, hA, 996, p[1], consts);
    // stage2: hA -> hB (Tout=992)
    stage_kernel<10><<<dim3(8, 2, cc), dim3(128), 0, stream>>>(
        hA, hB, 992, p[3], consts + 512);
    // stage3: hB -> hA (Tout=988)
    stage_kernel<10><<<dim3(8, 2, cc), dim3(128), 0, stream>>>(
        hB, hA, 988, p[5], consts + 1024);
    // conv4 + dense head
    final_kernel<<<dim3(cc), dim3(256), 0, stream>>>(
        hA, p[7], p[8], dnswT, p[22], (float*)d_out, b0);
  }
}